// Round 10
// baseline (6279.152 us; speedup 1.0000x reference)
//
#include <hip/hip_runtime.h>
#include <hip/hip_bf16.h>

typedef __attribute__((ext_vector_type(8))) short bf16x8;
typedef __attribute__((ext_vector_type(4))) float f32x4;

#define MFMA __builtin_amdgcn_mfma_f32_16x16x32_bf16

// ---------- helpers ----------
__device__ __forceinline__ short f2bf(float f) {
    union { __hip_bfloat16 h; short s; } u;
    u.h = __float2bfloat16(f);
    return u.s;
}

// ---------- fp32 [R][C] -> MFMA-fragment-tiled bf16 (no transpose) ----------
__global__ __launch_bounds__(64) void cvt_tile(const float* __restrict__ in,
                                               __hip_bfloat16* __restrict__ out, int C) {
    const int cd32 = C >> 5;
    const int tile = blockIdx.x;
    const int r16 = tile / cd32, c32 = tile - r16 * cd32;
    const int l = threadIdx.x;
    const int row = (r16 << 4) + (l & 15);
    const int c0 = (c32 << 5) + ((l >> 4) << 3);
    const float* src = in + (size_t)row * C + c0;
    short o[8];
#pragma unroll
    for (int j = 0; j < 8; ++j) o[j] = f2bf(src[j]);
    *(bf16x8*)((char*)out + (size_t)tile * 1024 + (l << 4)) = *(bf16x8*)o;
}

// ---------- fp32 W[K][N] -> fragment-tiled bf16 of W^T, LDS-staged coalesced ----------
__global__ __launch_bounds__(256) void tcvt256(const float* __restrict__ in,
                                               __hip_bfloat16* __restrict__ out,
                                               int N, int K) {
    __shared__ float tile[64][65];
    const int r0 = blockIdx.x << 6;  // K offset
    const int c0 = blockIdx.y << 6;  // N offset
    const int tid = threadIdx.x;
    const int row = tid >> 2, cq = tid & 3;
#pragma unroll
    for (int it = 0; it < 4; ++it) {
        int c4 = cq + (it << 2);
        float4 vv = *(const float4*)(in + (size_t)(r0 + row) * N + c0 + (c4 << 2));
        tile[row][(c4 << 2) + 0] = vv.x;
        tile[row][(c4 << 2) + 1] = vv.y;
        tile[row][(c4 << 2) + 2] = vv.z;
        tile[row][(c4 << 2) + 3] = vv.w;
    }
    __syncthreads();
    const int kd32 = K >> 5;
#pragma unroll
    for (int half = 0; half < 2; ++half) {
        int slot = tid + (half << 8);
        int ti = slot >> 6, l = slot & 63;
        int ci = ti & 3, ri = ti >> 2;
        short o[8];
#pragma unroll
        for (int j = 0; j < 8; ++j)
            o[j] = f2bf(tile[(ri << 5) + ((l >> 4) << 3) + j][(ci << 4) + (l & 15)]);
        size_t tidx = (size_t)((c0 >> 4) + ci) * kd32 + (r0 >> 5) + ri;
        *(bf16x8*)((char*)out + tidx * 1024 + (l << 4)) = *(bf16x8*)o;
    }
}

// ---------- core GEMM body: 64x64 tile, NW-wave K-split, both operands reg-direct ----------
// MODE 0: bf16 fragment-tiled out.  MODE 1: step epilogue (relu + input proj).
// MODE 2: decoder (fp32, [b][t][p]).
template <int MODE, int NW, int KC>
__device__ __forceinline__ void gemm_body(const char* __restrict__ Ab,
                                          const char* __restrict__ Bb,
                                          void* __restrict__ outp,
                                          const float* __restrict__ v,
                                          const float* __restrict__ Wi, int t,
                                          int bm, int bn, char* lds, int wv, int lane) {
    constexpr int KD32 = KC * NW;
    char* myl = lds + (wv << 14);
    const int kw0 = wv * KC;
    const int bm4 = bm << 2, bn4 = bn << 2;
    constexpr size_t FSTR = (size_t)KD32 << 10;
    const char* pA = Ab + (((size_t)(bm4 * KD32 + kw0)) << 10) + (lane << 4);
    const char* pB = Bb + (((size_t)(bn4 * KD32 + kw0)) << 10) + (lane << 4);

    f32x4 acc[4][4] = {};
    bf16x8 A00, A01, A02, A03, A10, A11, A12, A13,
           A20, A21, A22, A23, A30, A31, A32, A33;
    bf16x8 B00, B01, B02, B03, B10, B11, B12, B13,
           B20, B21, B22, B23, B30, B31, B32, B33;

#define LOADG(S, KI)                                       \
    do {                                                   \
        const char* pa_ = pA + ((size_t)(KI) << 10);       \
        const char* pb_ = pB + ((size_t)(KI) << 10);       \
        A##S##0 = *(const bf16x8*)(pa_);                   \
        A##S##1 = *(const bf16x8*)(pa_ + FSTR);            \
        A##S##2 = *(const bf16x8*)(pa_ + 2 * FSTR);        \
        A##S##3 = *(const bf16x8*)(pa_ + 3 * FSTR);        \
        B##S##0 = *(const bf16x8*)(pb_);                   \
        B##S##1 = *(const bf16x8*)(pb_ + FSTR);            \
        B##S##2 = *(const bf16x8*)(pb_ + 2 * FSTR);        \
        B##S##3 = *(const bf16x8*)(pb_ + 3 * FSTR);        \
    } while (0)

#define COMPUTE(S)                                             \
    do {                                                       \
        acc[0][0] = MFMA(A##S##0, B##S##0, acc[0][0], 0, 0, 0);\
        acc[0][1] = MFMA(A##S##0, B##S##1, acc[0][1], 0, 0, 0);\
        acc[0][2] = MFMA(A##S##0, B##S##2, acc[0][2], 0, 0, 0);\
        acc[0][3] = MFMA(A##S##0, B##S##3, acc[0][3], 0, 0, 0);\
        acc[1][0] = MFMA(A##S##1, B##S##0, acc[1][0], 0, 0, 0);\
        acc[1][1] = MFMA(A##S##1, B##S##1, acc[1][1], 0, 0, 0);\
        acc[1][2] = MFMA(A##S##1, B##S##2, acc[1][2], 0, 0, 0);\
        acc[1][3] = MFMA(A##S##1, B##S##3, acc[1][3], 0, 0, 0);\
        acc[2][0] = MFMA(A##S##2, B##S##0, acc[2][0], 0, 0, 0);\
        acc[2][1] = MFMA(A##S##2, B##S##1, acc[2][1], 0, 0, 0);\
        acc[2][2] = MFMA(A##S##2, B##S##2, acc[2][2], 0, 0, 0);\
        acc[2][3] = MFMA(A##S##2, B##S##3, acc[2][3], 0, 0, 0);\
        acc[3][0] = MFMA(A##S##3, B##S##0, acc[3][0], 0, 0, 0);\
        acc[3][1] = MFMA(A##S##3, B##S##1, acc[3][1], 0, 0, 0);\
        acc[3][2] = MFMA(A##S##3, B##S##2, acc[3][2], 0, 0, 0);\
        acc[3][3] = MFMA(A##S##3, B##S##3, acc[3][3], 0, 0, 0);\
    } while (0)

#define ITER(S, SP, DOISS, KI)                  \
    do {                                        \
        if (DOISS) LOADG(SP, (KI) + 3);         \
        __builtin_amdgcn_sched_barrier(0);      \
        COMPUTE(S);                             \
        __builtin_amdgcn_sched_barrier(0);      \
    } while (0)

    LOADG(0, 0);
    __builtin_amdgcn_sched_barrier(0);
    LOADG(1, 1);
    __builtin_amdgcn_sched_barrier(0);
    LOADG(2, 2);
    __builtin_amdgcn_sched_barrier(0);

    int s = 0;
    for (; s + 4 < KC; s += 4) {
        ITER(0, 3, true, s + 0);
        ITER(1, 0, true, s + 1);
        ITER(2, 1, true, s + 2);
        ITER(3, 2, true, s + 3);
    }
    ITER(0, 3, true,  s + 0);
    ITER(1, 0, false, s + 1);
    ITER(2, 1, false, s + 2);
    ITER(3, 2, false, s + 3);

#undef ITER
#undef COMPUTE
#undef LOADG

    // cross-wave K-reduction via LDS
    __syncthreads();  // (re-entry safety: previous use of lds done)
#pragma unroll
    for (int f = 0; f < 4; ++f)
#pragma unroll
        for (int g = 0; g < 4; ++g)
            *(f32x4*)(myl + (((f << 2) + g) << 10) + (lane << 4)) = acc[f][g];
    __syncthreads();

    constexpr int FPW = 16 / NW;
    f32x4 fin[FPW];
#pragma unroll
    for (int q = 0; q < FPW; ++q) {
        const int fid = wv * FPW + q;
        f32x4 ssum = {};
#pragma unroll
        for (int w = 0; w < NW; ++w)
            ssum += *(const f32x4*)(lds + (w << 14) + (fid << 10) + (lane << 4));
        fin[q] = ssum;
    }

    if constexpr (MODE == 0 || MODE == 1) {
        char* O = (char*)outp;
#pragma unroll
        for (int q = 0; q < FPW; ++q) {
            const int fid = wv * FPW + q;
            const int fr = fid >> 2, g = fid & 3;
            const int rbase = (bm << 6) + (fr << 4) + ((lane >> 4) << 2);
            const int c = (bn << 6) + (g << 4) + (lane & 15);
#pragma unroll
            for (int j = 0; j < 4; ++j) {
                int r = rbase + j;
                float val = fin[q][j];
                if constexpr (MODE == 1) {
                    float v0 = v[(size_t)(r * 100 + t) * 2 + 0];
                    float v1 = v[(size_t)(r * 100 + t) * 2 + 1];
                    val = fmaxf(val + v0 * Wi[c] + v1 * Wi[4096 + c], 0.0f);
                }
                size_t off = ((size_t)(r >> 4) * 128 + (c >> 5)) * 1024 +
                             ((size_t)((r & 15) + (((c >> 3) & 3) << 4)) << 4) +
                             ((c & 7) << 1);
                *(short*)(O + off) = f2bf(val);
            }
        }
    } else {
        float* O = (float*)outp;
#pragma unroll
        for (int q = 0; q < FPW; ++q) {
            const int fid = wv * FPW + q;
            const int fr = fid >> 2, g = fid & 3;
            const int rbase = (bm << 6) + (fr << 4) + ((lane >> 4) << 2);
            const int c = (bn << 6) + (g << 4) + (lane & 15);
#pragma unroll
            for (int j = 0; j < 4; ++j) {
                int r = rbase + j;
                int tt = r >> 8;
                int b = r & 255;
                O[((size_t)b * 100 + tt) * 512 + c] = fin[q][j];
            }
        }
    }
}

// ---------- device-scope grid barrier (256 co-resident blocks) ----------
__device__ __forceinline__ void gbar(int* cnt, int* gen, int nb) {
    __syncthreads();  // drains vmcnt(0): all block stores complete
    if (threadIdx.x == 0) {
        __threadfence();  // device-scope release of prior writes
        int g = __hip_atomic_load(gen, __ATOMIC_RELAXED, __HIP_MEMORY_SCOPE_AGENT);
        int vv = __hip_atomic_fetch_add(cnt, 1, __ATOMIC_ACQ_REL, __HIP_MEMORY_SCOPE_AGENT);
        if (vv == nb - 1) {
            __hip_atomic_store(cnt, 0, __ATOMIC_RELAXED, __HIP_MEMORY_SCOPE_AGENT);
            __hip_atomic_store(gen, g + 1, __ATOMIC_RELEASE, __HIP_MEMORY_SCOPE_AGENT);
        } else {
            while (__hip_atomic_load(gen, __ATOMIC_ACQUIRE, __HIP_MEMORY_SCOPE_AGENT) <= g)
                __builtin_amdgcn_s_sleep(8);
        }
        __threadfence();  // acquire side
    }
    __syncthreads();
}

// ---------- fused persistent kernel: h0 GEMM + 100 RNN steps ----------
__global__ __launch_bounds__(256, 1) void rnn_fused(const __hip_bfloat16* __restrict__ P0t,
                                                    const __hip_bfloat16* __restrict__ Wet,
                                                    const __hip_bfloat16* __restrict__ Wrt,
                                                    __hip_bfloat16* __restrict__ h0,
                                                    __hip_bfloat16* __restrict__ G,
                                                    const float* __restrict__ v,
                                                    const float* __restrict__ Wi,
                                                    int* __restrict__ bar) {
    __shared__ __align__(16) char lds[65536];
    const int id = blockIdx.x;
    const int xcd = id & 7, j = id >> 3;
    const int bn = (xcd << 3) + (j & 7);
    const int bm = j >> 3;
    const int tid = threadIdx.x, wv = tid >> 6, lane = tid & 63;

    // phase 1: h0 = P0 @ W_enc (K=512)
    gemm_body<0, 4, 4>((const char*)P0t, (const char*)Wet, (void*)h0,
                       nullptr, nullptr, 0, bm, bn, lds, wv, lane);
    gbar(bar, bar + 1, 256);

    // phase 2: 100 recurrent steps (K=4096)
#pragma unroll 1
    for (int t = 0; t < 100; ++t) {
        const char* Ab = (t == 0) ? (const char*)h0 : (const char*)(G + (size_t)(t - 1) * 1048576);
        gemm_body<1, 4, 32>(Ab, (const char*)Wrt, (void*)(G + (size_t)t * 1048576),
                            v, Wi, t, bm, bn, lds, wv, lane);
        if (t != 99) gbar(bar, bar + 1, 256);
    }
}

// ---------- standalone decoder (round-9 structure, unchanged) ----------
template <int MODE, int NW, int KC>
__global__ __launch_bounds__(NW * 64) void gemm_r(const __hip_bfloat16* __restrict__ A,
                                                  const __hip_bfloat16* __restrict__ B,
                                                  void* __restrict__ outp,
                                                  const float* __restrict__ v,
                                                  const float* __restrict__ Wi, int t) {
    __shared__ __align__(16) char lds[NW * 16384];
    const int id = blockIdx.x;
    int bm, bn;
    if constexpr (MODE == 2) {
        int xcd = id & 7, idx = id >> 3;
        int sw = xcd * 400 + idx;
        bm = sw >> 3;
        bn = sw & 7;
    } else {
        int xcd = id & 7, j = id >> 3;
        bn = (xcd << 3) + (j & 7);
        bm = j >> 3;
    }
    const int tid = threadIdx.x, wv = tid >> 6, lane = tid & 63;
    gemm_body<MODE, NW, KC>((const char*)A, (const char*)B, outp, v, Wi, t,
                            bm, bn, lds, wv, lane);
}

// ---------- launch ----------
extern "C" void kernel_launch(void* const* d_in, const int* in_sizes, int n_in,
                              void* d_out, int out_size, void* d_ws, size_t ws_size,
                              hipStream_t stream) {
    const float* v     = (const float*)d_in[0];  // [256][100][2]
    const float* P0    = (const float*)d_in[1];  // [256][512]
    const float* W_enc = (const float*)d_in[2];  // [512][4096]
    const float* W_in  = (const float*)d_in[3];  // [2][4096]
    const float* W_rec = (const float*)d_in[4];  // [4096][4096]
    const float* W_dec = (const float*)d_in[5];  // [4096][512]
    float* out = (float*)d_out;                  // [256][100][512]

    char* ws = (char*)d_ws;
    int* bar = (int*)(ws + 0);                                // [cnt, gen] (+pad to 256)
    __hip_bfloat16* Wrt = (__hip_bfloat16*)(ws + 256);        // W_rec^T tiled (32 MB)
    __hip_bfloat16* Wet = (__hip_bfloat16*)(ws + 33554688);   // W_enc^T tiled (4 MB)
    __hip_bfloat16* Wdt = (__hip_bfloat16*)(ws + 37748992);   // W_dec^T tiled (4 MB)
    __hip_bfloat16* P0t = (__hip_bfloat16*)(ws + 41943296);   // P0 tiled (256 KB)
    __hip_bfloat16* h0  = (__hip_bfloat16*)(ws + 42205440);   // h0 tiled (2 MB)
    __hip_bfloat16* G   = (__hip_bfloat16*)(ws + 44302592);   // 100 tiled slabs (200 MB)

    hipMemsetAsync(bar, 0, 256, stream);

    tcvt256<<<dim3(64, 64), 256, 0, stream>>>(W_rec, Wrt, 4096, 4096);
    tcvt256<<<dim3(8, 64), 256, 0, stream>>>(W_enc, Wet, 4096, 512);
    tcvt256<<<dim3(64, 8), 256, 0, stream>>>(W_dec, Wdt, 512, 4096);
    cvt_tile<<<256, 64, 0, stream>>>(P0, P0t, 512);

    // fused h0 + 100 steps (persistent, 1 block/CU, grid barriers between steps)
    rnn_fused<<<256, 256, 0, stream>>>(P0t, Wet, Wrt, h0, G, v, W_in, bar);

    // decoder: [25600][4096] tiled @ Wdt -> d_out
    gemm_r<2, 4, 32><<<3200, 256, 0, stream>>>(G, Wdt, (void*)out, nullptr, nullptr, 0);
}

// Round 11
// 1524.942 us; speedup vs baseline: 4.1176x; 4.1176x over previous
//
#include <hip/hip_runtime.h>
#include <hip/hip_bf16.h>

typedef __attribute__((ext_vector_type(8))) short bf16x8;
typedef __attribute__((ext_vector_type(4))) float f32x4;

#define MFMA __builtin_amdgcn_mfma_f32_16x16x32_bf16

// ---------- helpers ----------
__device__ __forceinline__ short f2bf(float f) {
    union { __hip_bfloat16 h; short s; } u;
    u.h = __float2bfloat16(f);
    return u.s;
}

// ---------- fp32 [R][C] -> MFMA-fragment-tiled bf16 (no transpose) ----------
// tile (r16, c32): lane l holds (row=l&15, k=(l>>4)*8+j) at tile*1024 + l*16 + j*2
__global__ __launch_bounds__(64) void cvt_tile(const float* __restrict__ in,
                                               __hip_bfloat16* __restrict__ out, int C) {
    const int cd32 = C >> 5;
    const int tile = blockIdx.x;
    const int r16 = tile / cd32, c32 = tile - r16 * cd32;
    const int l = threadIdx.x;
    const int row = (r16 << 4) + (l & 15);
    const int c0 = (c32 << 5) + ((l >> 4) << 3);
    const float* src = in + (size_t)row * C + c0;
    short o[8];
#pragma unroll
    for (int j = 0; j < 8; ++j) o[j] = f2bf(src[j]);
    *(bf16x8*)((char*)out + (size_t)tile * 1024 + (l << 4)) = *(bf16x8*)o;
}

// ---------- fp32 W[K][N] -> fragment-tiled bf16 of W^T, LDS-staged coalesced ----------
__global__ __launch_bounds__(256) void tcvt256(const float* __restrict__ in,
                                               __hip_bfloat16* __restrict__ out,
                                               int N, int K) {
    __shared__ float tile[64][65];
    const int r0 = blockIdx.x << 6;  // K offset
    const int c0 = blockIdx.y << 6;  // N offset
    const int tid = threadIdx.x;
    const int row = tid >> 2, cq = tid & 3;
#pragma unroll
    for (int it = 0; it < 4; ++it) {
        int c4 = cq + (it << 2);
        float4 vv = *(const float4*)(in + (size_t)(r0 + row) * N + c0 + (c4 << 2));
        tile[row][(c4 << 2) + 0] = vv.x;
        tile[row][(c4 << 2) + 1] = vv.y;
        tile[row][(c4 << 2) + 2] = vv.z;
        tile[row][(c4 << 2) + 3] = vv.w;
    }
    __syncthreads();
    const int kd32 = K >> 5;
#pragma unroll
    for (int half = 0; half < 2; ++half) {
        int slot = tid + (half << 8);
        int ti = slot >> 6, l = slot & 63;
        int ci = ti & 3, ri = ti >> 2;
        short o[8];
#pragma unroll
        for (int j = 0; j < 8; ++j)
            o[j] = f2bf(tile[(ri << 5) + ((l >> 4) << 3) + j][(ci << 4) + (l & 15)]);
        size_t tidx = (size_t)((c0 >> 4) + ci) * kd32 + (r0 >> 5) + ri;
        *(bf16x8*)((char*)out + tidx * 1024 + (l << 4)) = *(bf16x8*)o;
    }
}

// ---------- per-wave K-split GEMM (h0 + steps): round-9 structure, unchanged ----------
// MODE 0: h0 (bf16 fragment-tiled out).  MODE 1: step (relu + input proj).
template <int MODE, int NW, int KC>
__global__ __launch_bounds__(NW * 64) void gemm_r(const __hip_bfloat16* __restrict__ A,
                                                  const __hip_bfloat16* __restrict__ B,
                                                  void* __restrict__ outp,
                                                  const float* __restrict__ v,
                                                  const float* __restrict__ Wi, int t) {
    constexpr int KD32 = KC * NW;  // K/32 total
    __shared__ __align__(16) char lds[NW * 16384];  // reduction only
    const int id = blockIdx.x;
    const int xcd = id & 7, j = id >> 3;
    const int bn = (xcd << 3) + (j & 7);
    const int bm = j >> 3;
    const int tid = threadIdx.x, wv = tid >> 6, lane = tid & 63;
    char* myl = lds + (wv << 14);
    const int kw0 = wv * KC;
    const int bm4 = bm << 2, bn4 = bn << 2;

    constexpr size_t FSTR = (size_t)KD32 << 10;
    const char* pA = (const char*)A + (((size_t)(bm4 * KD32 + kw0)) << 10) + (lane << 4);
    const char* pB = (const char*)B + (((size_t)(bn4 * KD32 + kw0)) << 10) + (lane << 4);

    f32x4 acc[4][4] = {};
    bf16x8 A00, A01, A02, A03, A10, A11, A12, A13,
           A20, A21, A22, A23, A30, A31, A32, A33;
    bf16x8 B00, B01, B02, B03, B10, B11, B12, B13,
           B20, B21, B22, B23, B30, B31, B32, B33;

#define LOADG(S, KI)                                       \
    do {                                                   \
        const char* pa_ = pA + ((size_t)(KI) << 10);       \
        const char* pb_ = pB + ((size_t)(KI) << 10);       \
        A##S##0 = *(const bf16x8*)(pa_);                   \
        A##S##1 = *(const bf16x8*)(pa_ + FSTR);            \
        A##S##2 = *(const bf16x8*)(pa_ + 2 * FSTR);        \
        A##S##3 = *(const bf16x8*)(pa_ + 3 * FSTR);        \
        B##S##0 = *(const bf16x8*)(pb_);                   \
        B##S##1 = *(const bf16x8*)(pb_ + FSTR);            \
        B##S##2 = *(const bf16x8*)(pb_ + 2 * FSTR);        \
        B##S##3 = *(const bf16x8*)(pb_ + 3 * FSTR);        \
    } while (0)

#define COMPUTE(S)                                             \
    do {                                                       \
        acc[0][0] = MFMA(A##S##0, B##S##0, acc[0][0], 0, 0, 0);\
        acc[0][1] = MFMA(A##S##0, B##S##1, acc[0][1], 0, 0, 0);\
        acc[0][2] = MFMA(A##S##0, B##S##2, acc[0][2], 0, 0, 0);\
        acc[0][3] = MFMA(A##S##0, B##S##3, acc[0][3], 0, 0, 0);\
        acc[1][0] = MFMA(A##S##1, B##S##0, acc[1][0], 0, 0, 0);\
        acc[1][1] = MFMA(A##S##1, B##S##1, acc[1][1], 0, 0, 0);\
        acc[1][2] = MFMA(A##S##1, B##S##2, acc[1][2], 0, 0, 0);\
        acc[1][3] = MFMA(A##S##1, B##S##3, acc[1][3], 0, 0, 0);\
        acc[2][0] = MFMA(A##S##2, B##S##0, acc[2][0], 0, 0, 0);\
        acc[2][1] = MFMA(A##S##2, B##S##1, acc[2][1], 0, 0, 0);\
        acc[2][2] = MFMA(A##S##2, B##S##2, acc[2][2], 0, 0, 0);\
        acc[2][3] = MFMA(A##S##2, B##S##3, acc[2][3], 0, 0, 0);\
        acc[3][0] = MFMA(A##S##3, B##S##0, acc[3][0], 0, 0, 0);\
        acc[3][1] = MFMA(A##S##3, B##S##1, acc[3][1], 0, 0, 0);\
        acc[3][2] = MFMA(A##S##3, B##S##2, acc[3][2], 0, 0, 0);\
        acc[3][3] = MFMA(A##S##3, B##S##3, acc[3][3], 0, 0, 0);\
    } while (0)

#define ITER(S, SP, DOISS, KI)                  \
    do {                                        \
        if (DOISS) LOADG(SP, (KI) + 3);         \
        __builtin_amdgcn_sched_barrier(0);      \
        COMPUTE(S);                             \
        __builtin_amdgcn_sched_barrier(0);      \
    } while (0)

    LOADG(0, 0);
    __builtin_amdgcn_sched_barrier(0);
    LOADG(1, 1);
    __builtin_amdgcn_sched_barrier(0);
    LOADG(2, 2);
    __builtin_amdgcn_sched_barrier(0);

    int s = 0;
    for (; s + 4 < KC; s += 4) {
        ITER(0, 3, true, s + 0);
        ITER(1, 0, true, s + 1);
        ITER(2, 1, true, s + 2);
        ITER(3, 2, true, s + 3);
    }
    ITER(0, 3, true,  s + 0);
    ITER(1, 0, false, s + 1);
    ITER(2, 1, false, s + 2);
    ITER(3, 2, false, s + 3);

#undef ITER
#undef COMPUTE
#undef LOADG

    // cross-wave K-reduction via LDS
#pragma unroll
    for (int f = 0; f < 4; ++f)
#pragma unroll
        for (int g = 0; g < 4; ++g)
            *(f32x4*)(myl + (((f << 2) + g) << 10) + (lane << 4)) = acc[f][g];
    __syncthreads();

    constexpr int FPW = 16 / NW;
    f32x4 fin[FPW];
#pragma unroll
    for (int q = 0; q < FPW; ++q) {
        const int fid = wv * FPW + q;
        f32x4 ssum = {};
#pragma unroll
        for (int w = 0; w < NW; ++w)
            ssum += *(const f32x4*)(lds + (w << 14) + (fid << 10) + (lane << 4));
        fin[q] = ssum;
    }

    char* O = (char*)outp;
#pragma unroll
    for (int q = 0; q < FPW; ++q) {
        const int fid = wv * FPW + q;
        const int fr = fid >> 2, g = fid & 3;
        const int rbase = (bm << 6) + (fr << 4) + ((lane >> 4) << 2);
        const int c = (bn << 6) + (g << 4) + (lane & 15);
#pragma unroll
        for (int j = 0; j < 4; ++j) {
            int r = rbase + j;
            float val = fin[q][j];
            if constexpr (MODE == 1) {
                float v0 = v[(size_t)(r * 100 + t) * 2 + 0];
                float v1 = v[(size_t)(r * 100 + t) * 2 + 1];
                val = fmaxf(val + v0 * Wi[c] + v1 * Wi[4096 + c], 0.0f);
            }
            size_t off = ((size_t)(r >> 4) * 128 + (c >> 5)) * 1024 +
                         ((size_t)((r & 15) + (((c >> 3) & 3) << 4)) << 4) +
                         ((c & 7) << 1);
            *(short*)(O + off) = f2bf(val);
        }
    }
}

// ---------- decoder: 128x128 tile, 4 waves (2x2 x 64x64), full-K, reg-direct ----------
// A = G (100 fragment-tiled slabs of [256 rows][4096]), B = Wdt (fragment-tiled
// W_dec^T, 32 n16-rows x 128 k32). fp32 out[b][t][p]. 800 blocks, no LDS.
__global__ __launch_bounds__(256) void gemm_d(const __hip_bfloat16* __restrict__ G,
                                              const __hip_bfloat16* __restrict__ Wdt,
                                              float* __restrict__ out) {
    constexpr int KD32 = 128;
    const int id = blockIdx.x;               // 800 = 8 XCD x 100
    const int xcd = id & 7, idx = id >> 3;
    const int sw = xcd * 100 + idx;
    const int bm = sw >> 2;                  // 0..199 (128-row tiles)
    const int bn = sw & 3;                   // 0..3   (128-col tiles)
    const int tid = threadIdx.x, wv = tid >> 6, lane = tid & 63;
    const int wr = wv >> 1, wc = wv & 1;

    const int slab = bm >> 1, half = bm & 1;
    constexpr size_t FSTR = (size_t)KD32 << 10;  // 131072: fragment-row stride
    const char* pA = (const char*)G + (size_t)slab * 2097152 +
                     ((size_t)((half << 3) + (wr << 2)) << 17) + (lane << 4);
    const char* pB = (const char*)Wdt +
                     ((size_t)((bn << 3) + (wc << 2)) << 17) + (lane << 4);

    f32x4 acc[4][4] = {};
    bf16x8 A00, A01, A02, A03, A10, A11, A12, A13,
           A20, A21, A22, A23, A30, A31, A32, A33;
    bf16x8 B00, B01, B02, B03, B10, B11, B12, B13,
           B20, B21, B22, B23, B30, B31, B32, B33;

#define LOADG(S, KI)                                       \
    do {                                                   \
        const char* pa_ = pA + ((size_t)(KI) << 10);       \
        const char* pb_ = pB + ((size_t)(KI) << 10);       \
        A##S##0 = *(const bf16x8*)(pa_);                   \
        A##S##1 = *(const bf16x8*)(pa_ + FSTR);            \
        A##S##2 = *(const bf16x8*)(pa_ + 2 * FSTR);        \
        A##S##3 = *(const bf16x8*)(pa_ + 3 * FSTR);        \
        B##S##0 = *(const bf16x8*)(pb_);                   \
        B##S##1 = *(const bf16x8*)(pb_ + FSTR);            \
        B##S##2 = *(const bf16x8*)(pb_ + 2 * FSTR);        \
        B##S##3 = *(const bf16x8*)(pb_ + 3 * FSTR);        \
    } while (0)

#define COMPUTE(S)                                             \
    do {                                                       \
        acc[0][0] = MFMA(A##S##0, B##S##0, acc[0][0], 0, 0, 0);\
        acc[0][1] = MFMA(A##S##0, B##S##1, acc[0][1], 0, 0, 0);\
        acc[0][2] = MFMA(A##S##0, B##S##2, acc[0][2], 0, 0, 0);\
        acc[0][3] = MFMA(A##S##0, B##S##3, acc[0][3], 0, 0, 0);\
        acc[1][0] = MFMA(A##S##1, B##S##0, acc[1][0], 0, 0, 0);\
        acc[1][1] = MFMA(A##S##1, B##S##1, acc[1][1], 0, 0, 0);\
        acc[1][2] = MFMA(A##S##1, B##S##2, acc[1][2], 0, 0, 0);\
        acc[1][3] = MFMA(A##S##1, B##S##3, acc[1][3], 0, 0, 0);\
        acc[2][0] = MFMA(A##S##2, B##S##0, acc[2][0], 0, 0, 0);\
        acc[2][1] = MFMA(A##S##2, B##S##1, acc[2][1], 0, 0, 0);\
        acc[2][2] = MFMA(A##S##2, B##S##2, acc[2][2], 0, 0, 0);\
        acc[2][3] = MFMA(A##S##2, B##S##3, acc[2][3], 0, 0, 0);\
        acc[3][0] = MFMA(A##S##3, B##S##0, acc[3][0], 0, 0, 0);\
        acc[3][1] = MFMA(A##S##3, B##S##1, acc[3][1], 0, 0, 0);\
        acc[3][2] = MFMA(A##S##3, B##S##2, acc[3][2], 0, 0, 0);\
        acc[3][3] = MFMA(A##S##3, B##S##3, acc[3][3], 0, 0, 0);\
    } while (0)

#define ITER(S, SP, DOISS, KI)                  \
    do {                                        \
        if (DOISS) LOADG(SP, (KI) + 3);         \
        __builtin_amdgcn_sched_barrier(0);      \
        COMPUTE(S);                             \
        __builtin_amdgcn_sched_barrier(0);      \
    } while (0)

    LOADG(0, 0);
    __builtin_amdgcn_sched_barrier(0);
    LOADG(1, 1);
    __builtin_amdgcn_sched_barrier(0);
    LOADG(2, 2);
    __builtin_amdgcn_sched_barrier(0);

    int s = 0;
    for (; s + 4 < KD32; s += 4) {
        ITER(0, 3, true, s + 0);
        ITER(1, 0, true, s + 1);
        ITER(2, 1, true, s + 2);
        ITER(3, 2, true, s + 3);
    }
    ITER(0, 3, true,  s + 0);
    ITER(1, 0, false, s + 1);
    ITER(2, 1, false, s + 2);
    ITER(3, 2, false, s + 3);

#undef ITER
#undef COMPUTE
#undef LOADG

    // epilogue: wave (wr,wc) owns rows [bm*128+wr*64, +64) x cols [bn*128+wc*64, +64)
#pragma unroll
    for (int f = 0; f < 4; ++f) {
        const int rbase = (bm << 7) + (wr << 6) + (f << 4) + ((lane >> 4) << 2);
#pragma unroll
        for (int g = 0; g < 4; ++g) {
            const int c = (bn << 7) + (wc << 6) + (g << 4) + (lane & 15);
#pragma unroll
            for (int j = 0; j < 4; ++j) {
                int r = rbase + j;
                int tt = r >> 8;
                int b = r & 255;
                out[((size_t)b * 100 + tt) * 512 + c] = acc[f][g][j];
            }
        }
    }
}

// ---------- launch ----------
extern "C" void kernel_launch(void* const* d_in, const int* in_sizes, int n_in,
                              void* d_out, int out_size, void* d_ws, size_t ws_size,
                              hipStream_t stream) {
    const float* v     = (const float*)d_in[0];  // [256][100][2]
    const float* P0    = (const float*)d_in[1];  // [256][512]
    const float* W_enc = (const float*)d_in[2];  // [512][4096]
    const float* W_in  = (const float*)d_in[3];  // [2][4096]
    const float* W_rec = (const float*)d_in[4];  // [4096][4096]
    const float* W_dec = (const float*)d_in[5];  // [4096][512]
    float* out = (float*)d_out;                  // [256][100][512]

    char* ws = (char*)d_ws;
    __hip_bfloat16* Wrt = (__hip_bfloat16*)(ws + 0);          // W_rec^T tiled
    __hip_bfloat16* Wet = (__hip_bfloat16*)(ws + 33554432);   // W_enc^T tiled
    __hip_bfloat16* Wdt = (__hip_bfloat16*)(ws + 37748736);   // W_dec^T tiled
    __hip_bfloat16* P0t = (__hip_bfloat16*)(ws + 41943040);   // P0 tiled
    __hip_bfloat16* h0  = (__hip_bfloat16*)(ws + 42205184);   // h0 tiled
    __hip_bfloat16* G   = (__hip_bfloat16*)(ws + 44302336);   // 100 tiled slabs

    tcvt256<<<dim3(64, 64), 256, 0, stream>>>(W_rec, Wrt, 4096, 4096);
    tcvt256<<<dim3(8, 64), 256, 0, stream>>>(W_enc, Wet, 4096, 512);
    tcvt256<<<dim3(64, 8), 256, 0, stream>>>(W_dec, Wdt, 512, 4096);
    cvt_tile<<<256, 64, 0, stream>>>(P0, P0t, 512);

    // h0 = P0 @ W_enc   (K=512: NW=4, KC=4)
    gemm_r<0, 4, 4><<<256, 256, 0, stream>>>(P0t, Wet, (void*)h0, nullptr, nullptr, 0);

    // recurrent steps (K=4096: NW=4, KC=32)
    for (int t = 0; t < 100; ++t) {
        const __hip_bfloat16* hprev = (t == 0) ? h0 : (G + (size_t)(t - 1) * 1048576);
        gemm_r<1, 4, 32><<<256, 256, 0, stream>>>(hprev, Wrt,
                                                  (void*)(G + (size_t)t * 1048576), v, W_in, t);
    }

    // decoder: 128x128 tiles, 800 blocks
    gemm_d<<<800, 256, 0, stream>>>(G, Wdt, out);
}

// Round 12
// 1468.988 us; speedup vs baseline: 4.2745x; 1.0381x over previous
//
#include <hip/hip_runtime.h>
#include <hip/hip_bf16.h>

typedef __attribute__((ext_vector_type(8))) short bf16x8;
typedef __attribute__((ext_vector_type(4))) float f32x4;

#define MFMA __builtin_amdgcn_mfma_f32_16x16x32_bf16

// ---------- helpers ----------
__device__ __forceinline__ short f2bf(float f) {
    union { __hip_bfloat16 h; short s; } u;
    u.h = __float2bfloat16(f);
    return u.s;
}

__device__ __forceinline__ void gld_lds16(const void* g, void* l) {
    auto gp = (const __attribute__((address_space(1))) void*)(g);
    auto lp = (__attribute__((address_space(3))) void*)(l);
    __builtin_amdgcn_global_load_lds(gp, lp, 16, 0, 0);
}

// ---------- fp32 [R][C] -> MFMA-fragment-tiled bf16 (no transpose) ----------
// tile (r16, c32): lane l holds (row=l&15, k=(l>>4)*8+j) at tile*1024 + l*16 + j*2
__global__ __launch_bounds__(64) void cvt_tile(const float* __restrict__ in,
                                               __hip_bfloat16* __restrict__ out, int C) {
    const int cd32 = C >> 5;
    const int tile = blockIdx.x;
    const int r16 = tile / cd32, c32 = tile - r16 * cd32;
    const int l = threadIdx.x;
    const int row = (r16 << 4) + (l & 15);
    const int c0 = (c32 << 5) + ((l >> 4) << 3);
    const float* src = in + (size_t)row * C + c0;
    short o[8];
#pragma unroll
    for (int j = 0; j < 8; ++j) o[j] = f2bf(src[j]);
    *(bf16x8*)((char*)out + (size_t)tile * 1024 + (l << 4)) = *(bf16x8*)o;
}

// ---------- fp32 W[K][N] -> fragment-tiled bf16 of W^T, LDS-staged coalesced ----------
__global__ __launch_bounds__(256) void tcvt256(const float* __restrict__ in,
                                               __hip_bfloat16* __restrict__ out,
                                               int N, int K) {
    __shared__ float tile[64][65];
    const int r0 = blockIdx.x << 6;  // K offset
    const int c0 = blockIdx.y << 6;  // N offset
    const int tid = threadIdx.x;
    const int row = tid >> 2, cq = tid & 3;
#pragma unroll
    for (int it = 0; it < 4; ++it) {
        int c4 = cq + (it << 2);
        float4 vv = *(const float4*)(in + (size_t)(r0 + row) * N + c0 + (c4 << 2));
        tile[row][(c4 << 2) + 0] = vv.x;
        tile[row][(c4 << 2) + 1] = vv.y;
        tile[row][(c4 << 2) + 2] = vv.z;
        tile[row][(c4 << 2) + 3] = vv.w;
    }
    __syncthreads();
    const int kd32 = K >> 5;
#pragma unroll
    for (int half = 0; half < 2; ++half) {
        int slot = tid + (half << 8);
        int ti = slot >> 6, l = slot & 63;
        int ci = ti & 3, ri = ti >> 2;
        short o[8];
#pragma unroll
        for (int j = 0; j < 8; ++j)
            o[j] = f2bf(tile[(ri << 5) + ((l >> 4) << 3) + j][(ci << 4) + (l & 15)]);
        size_t tidx = (size_t)((c0 >> 4) + ci) * kd32 + (r0 >> 5) + ri;
        *(bf16x8*)((char*)out + tidx * 1024 + (l << 4)) = *(bf16x8*)o;
    }
}

// ---------- per-wave K-split GEMM (h0 + steps): round-9 structure, unchanged ----------
// MODE 0: h0 (bf16 fragment-tiled out).  MODE 1: step (relu + input proj).
template <int MODE, int NW, int KC>
__global__ __launch_bounds__(NW * 64) void gemm_r(const __hip_bfloat16* __restrict__ A,
                                                  const __hip_bfloat16* __restrict__ B,
                                                  void* __restrict__ outp,
                                                  const float* __restrict__ v,
                                                  const float* __restrict__ Wi, int t) {
    constexpr int KD32 = KC * NW;  // K/32 total
    __shared__ __align__(16) char lds[NW * 16384];  // reduction only
    const int id = blockIdx.x;
    const int xcd = id & 7, j = id >> 3;
    const int bn = (xcd << 3) + (j & 7);
    const int bm = j >> 3;
    const int tid = threadIdx.x, wv = tid >> 6, lane = tid & 63;
    char* myl = lds + (wv << 14);
    const int kw0 = wv * KC;
    const int bm4 = bm << 2, bn4 = bn << 2;

    constexpr size_t FSTR = (size_t)KD32 << 10;
    const char* pA = (const char*)A + (((size_t)(bm4 * KD32 + kw0)) << 10) + (lane << 4);
    const char* pB = (const char*)B + (((size_t)(bn4 * KD32 + kw0)) << 10) + (lane << 4);

    f32x4 acc[4][4] = {};
    bf16x8 A00, A01, A02, A03, A10, A11, A12, A13,
           A20, A21, A22, A23, A30, A31, A32, A33;
    bf16x8 B00, B01, B02, B03, B10, B11, B12, B13,
           B20, B21, B22, B23, B30, B31, B32, B33;

#define LOADG(S, KI)                                       \
    do {                                                   \
        const char* pa_ = pA + ((size_t)(KI) << 10);       \
        const char* pb_ = pB + ((size_t)(KI) << 10);       \
        A##S##0 = *(const bf16x8*)(pa_);                   \
        A##S##1 = *(const bf16x8*)(pa_ + FSTR);            \
        A##S##2 = *(const bf16x8*)(pa_ + 2 * FSTR);        \
        A##S##3 = *(const bf16x8*)(pa_ + 3 * FSTR);        \
        B##S##0 = *(const bf16x8*)(pb_);                   \
        B##S##1 = *(const bf16x8*)(pb_ + FSTR);            \
        B##S##2 = *(const bf16x8*)(pb_ + 2 * FSTR);        \
        B##S##3 = *(const bf16x8*)(pb_ + 3 * FSTR);        \
    } while (0)

#define COMPUTE(S)                                             \
    do {                                                       \
        acc[0][0] = MFMA(A##S##0, B##S##0, acc[0][0], 0, 0, 0);\
        acc[0][1] = MFMA(A##S##0, B##S##1, acc[0][1], 0, 0, 0);\
        acc[0][2] = MFMA(A##S##0, B##S##2, acc[0][2], 0, 0, 0);\
        acc[0][3] = MFMA(A##S##0, B##S##3, acc[0][3], 0, 0, 0);\
        acc[1][0] = MFMA(A##S##1, B##S##0, acc[1][0], 0, 0, 0);\
        acc[1][1] = MFMA(A##S##1, B##S##1, acc[1][1], 0, 0, 0);\
        acc[1][2] = MFMA(A##S##1, B##S##2, acc[1][2], 0, 0, 0);\
        acc[1][3] = MFMA(A##S##1, B##S##3, acc[1][3], 0, 0, 0);\
        acc[2][0] = MFMA(A##S##2, B##S##0, acc[2][0], 0, 0, 0);\
        acc[2][1] = MFMA(A##S##2, B##S##1, acc[2][1], 0, 0, 0);\
        acc[2][2] = MFMA(A##S##2, B##S##2, acc[2][2], 0, 0, 0);\
        acc[2][3] = MFMA(A##S##2, B##S##3, acc[2][3], 0, 0, 0);\
        acc[3][0] = MFMA(A##S##3, B##S##0, acc[3][0], 0, 0, 0);\
        acc[3][1] = MFMA(A##S##3, B##S##1, acc[3][1], 0, 0, 0);\
        acc[3][2] = MFMA(A##S##3, B##S##2, acc[3][2], 0, 0, 0);\
        acc[3][3] = MFMA(A##S##3, B##S##3, acc[3][3], 0, 0, 0);\
    } while (0)

#define ITER(S, SP, DOISS, KI)                  \
    do {                                        \
        if (DOISS) LOADG(SP, (KI) + 3);         \
        __builtin_amdgcn_sched_barrier(0);      \
        COMPUTE(S);                             \
        __builtin_amdgcn_sched_barrier(0);      \
    } while (0)

    LOADG(0, 0);
    __builtin_amdgcn_sched_barrier(0);
    LOADG(1, 1);
    __builtin_amdgcn_sched_barrier(0);
    LOADG(2, 2);
    __builtin_amdgcn_sched_barrier(0);

    int s = 0;
    for (; s + 4 < KC; s += 4) {
        ITER(0, 3, true, s + 0);
        ITER(1, 0, true, s + 1);
        ITER(2, 1, true, s + 2);
        ITER(3, 2, true, s + 3);
    }
    ITER(0, 3, true,  s + 0);
    ITER(1, 0, false, s + 1);
    ITER(2, 1, false, s + 2);
    ITER(3, 2, false, s + 3);

#undef ITER
#undef COMPUTE
#undef LOADG

    // cross-wave K-reduction via LDS
#pragma unroll
    for (int f = 0; f < 4; ++f)
#pragma unroll
        for (int g = 0; g < 4; ++g)
            *(f32x4*)(myl + (((f << 2) + g) << 10) + (lane << 4)) = acc[f][g];
    __syncthreads();

    constexpr int FPW = 16 / NW;
    f32x4 fin[FPW];
#pragma unroll
    for (int q = 0; q < FPW; ++q) {
        const int fid = wv * FPW + q;
        f32x4 ssum = {};
#pragma unroll
        for (int w = 0; w < NW; ++w)
            ssum += *(const f32x4*)(lds + (w << 14) + (fid << 10) + (lane << 4));
        fin[q] = ssum;
    }

    char* O = (char*)outp;
#pragma unroll
    for (int q = 0; q < FPW; ++q) {
        const int fid = wv * FPW + q;
        const int fr = fid >> 2, g = fid & 3;
        const int rbase = (bm << 6) + (fr << 4) + ((lane >> 4) << 2);
        const int c = (bn << 6) + (g << 4) + (lane & 15);
#pragma unroll
        for (int j = 0; j < 4; ++j) {
            int r = rbase + j;
            float val = fin[q][j];
            if constexpr (MODE == 1) {
                float v0 = v[(size_t)(r * 100 + t) * 2 + 0];
                float v1 = v[(size_t)(r * 100 + t) * 2 + 1];
                val = fmaxf(val + v0 * Wi[c] + v1 * Wi[4096 + c], 0.0f);
            }
            size_t off = ((size_t)(r >> 4) * 128 + (c >> 5)) * 1024 +
                         ((size_t)((r & 15) + (((c >> 3) & 3) << 4)) << 4) +
                         ((c & 7) << 1);
            *(short*)(O + off) = f2bf(val);
        }
    }
}

// ---------- decoder: 256x256 tile, 8 waves, B LDS-shared, A reg-direct ----------
// Block (t, nh): C rows = slab t (256 batches), cols = [nh*256, +256).
// Per k32-step: B = 16 frags (16KB) staged to LDS shared by all 8 waves;
// A = 2 wave-private frags direct to VGPR. Uniform 4-op issue groups
// [2 gld_lds + 2 A-loads], sched_barrier-pinned, vmcnt(8)/8/4/0, barrier/step.
// 200 blocks, 64KB LDS, acc 128 VGPR/lane.
__global__ __launch_bounds__(512) void gemm_dec(const __hip_bfloat16* __restrict__ G,
                                                const __hip_bfloat16* __restrict__ Wdt,
                                                float* __restrict__ out) {
    __shared__ __align__(16) char lds[65536];  // 4 bufs x 16KB
    const int id = blockIdx.x;                 // 200 = 100 t x 2 nh
    const int t = id >> 1, nh = id & 1;
    const int tid = threadIdx.x, wv = tid >> 6, lane = tid & 63;

    // A: slab t (2MB), wave's frag-rows 2wv, 2wv+1; 128 k32-tiles x 1KB each
    const char* pA = (const char*)G + (size_t)t * 2097152 +
                     ((size_t)(wv << 1) << 17) + (lane << 4);
    // B: Wdt frag-rows nh*16 .. nh*16+15 (each 131072 B apart)
    const char* pB = (const char*)Wdt + ((size_t)(nh << 4) << 17) + (lane << 4);

    f32x4 acc0[16] = {};  // rows wv*32 + [0,16)  x 16 col-frags
    f32x4 acc1[16] = {};  // rows wv*32 + [16,32) x 16 col-frags
    bf16x8 A00, A01, A10, A11, A20, A21, A30, A31;  // 4 slots x 2 frags

#define STAGE(SLOT, KI)                                                  \
    do {                                                                 \
        char* d_ = lds + ((SLOT) << 14);                                 \
        const char* b_ = pB + (((size_t)(wv << 1)) << 17) +              \
                         ((size_t)(KI) << 10);                           \
        gld_lds16(b_, d_ + ((wv << 1) << 10));                           \
        gld_lds16(b_ + (1 << 17), d_ + (((wv << 1) + 1) << 10));         \
    } while (0)

#define LOADA(S, KI)                                                     \
    do {                                                                 \
        const char* a_ = pA + ((size_t)(KI) << 10);                      \
        A##S##0 = *(const bf16x8*)(a_);                                  \
        A##S##1 = *(const bf16x8*)(a_ + (1 << 17));                      \
    } while (0)

#define COMPUTE(S)                                                       \
    do {                                                                 \
        const char* bb_ = lds + ((S) << 14) + (lane << 4);               \
        _Pragma("unroll") for (int f = 0; f < 16; ++f) {                 \
            bf16x8 b_ = *(const bf16x8*)(bb_ + (f << 10));               \
            acc0[f] = MFMA(A##S##0, b_, acc0[f], 0, 0, 0);               \
            acc1[f] = MFMA(A##S##1, b_, acc1[f], 0, 0, 0);               \
        }                                                                \
    } while (0)

#define ITER(S, SP, VM, DOISS, KI)                                 \
    do {                                                           \
        asm volatile("s_waitcnt vmcnt(%0)" ::"i"(VM) : "memory");  \
        __builtin_amdgcn_s_barrier();                              \
        __builtin_amdgcn_sched_barrier(0);                         \
        if (DOISS) {                                               \
            STAGE(SP, (KI) + 3);                                   \
            LOADA(SP, (KI) + 3);                                   \
        }                                                          \
        __builtin_amdgcn_sched_barrier(0);                         \
        COMPUTE(S);                                                \
    } while (0)

    // prologue: 3 pinned uniform groups [2 gld_lds + 2 A] = 12 outstanding
    STAGE(0, 0); LOADA(0, 0);
    __builtin_amdgcn_sched_barrier(0);
    STAGE(1, 1); LOADA(1, 1);
    __builtin_amdgcn_sched_barrier(0);
    STAGE(2, 2); LOADA(2, 2);
    __builtin_amdgcn_sched_barrier(0);

    int s = 0;
    for (; s + 4 < 128; s += 4) {
        ITER(0, 3, 8, true, s + 0);
        ITER(1, 0, 8, true, s + 1);
        ITER(2, 1, 8, true, s + 2);
        ITER(3, 2, 8, true, s + 3);
    }
    // tail (s == 124)
    ITER(0, 3, 8, true,  s + 0);   // stages k-tile 127
    ITER(1, 0, 8, false, s + 1);
    ITER(2, 1, 4, false, s + 2);
    ITER(3, 2, 0, false, s + 3);

#undef ITER
#undef COMPUTE
#undef LOADA
#undef STAGE

    // epilogue: wave wv rows [wv*32, +32), cols [nh*256, +256)
    const int rb = (wv << 5) + ((lane >> 4) << 2);
    const int cb = (nh << 8) + (lane & 15);
#pragma unroll
    for (int f = 0; f < 16; ++f) {
        const int c = cb + (f << 4);
#pragma unroll
        for (int j = 0; j < 4; ++j) {
            int b0 = rb + j;
            int b1 = rb + 16 + j;
            out[((size_t)b0 * 100 + t) * 512 + c] = acc0[f][j];
            out[((size_t)b1 * 100 + t) * 512 + c] = acc1[f][j];
        }
    }
}

// ---------- launch ----------
extern "C" void kernel_launch(void* const* d_in, const int* in_sizes, int n_in,
                              void* d_out, int out_size, void* d_ws, size_t ws_size,
                              hipStream_t stream) {
    const float* v     = (const float*)d_in[0];  // [256][100][2]
    const float* P0    = (const float*)d_in[1];  // [256][512]
    const float* W_enc = (const float*)d_in[2];  // [512][4096]
    const float* W_in  = (const float*)d_in[3];  // [2][4096]
    const float* W_rec = (const float*)d_in[4];  // [4096][4096]
    const float* W_dec = (const float*)d_in[5];  // [4096][512]
    float* out = (float*)d_out;                  // [256][100][512]

    char* ws = (char*)d_ws;
    __hip_bfloat16* Wrt = (__hip_bfloat16*)(ws + 0);          // W_rec^T tiled
    __hip_bfloat16* Wet = (__hip_bfloat16*)(ws + 33554432);   // W_enc^T tiled
    __hip_bfloat16* Wdt = (__hip_bfloat16*)(ws + 37748736);   // W_dec^T tiled
    __hip_bfloat16* P0t = (__hip_bfloat16*)(ws + 41943040);   // P0 tiled
    __hip_bfloat16* h0  = (__hip_bfloat16*)(ws + 42205184);   // h0 tiled
    __hip_bfloat16* G   = (__hip_bfloat16*)(ws + 44302336);   // 100 tiled slabs

    tcvt256<<<dim3(64, 64), 256, 0, stream>>>(W_rec, Wrt, 4096, 4096);
    tcvt256<<<dim3(8, 64), 256, 0, stream>>>(W_enc, Wet, 4096, 512);
    tcvt256<<<dim3(64, 8), 256, 0, stream>>>(W_dec, Wdt, 512, 4096);
    cvt_tile<<<256, 64, 0, stream>>>(P0, P0t, 512);

    // h0 = P0 @ W_enc   (K=512: NW=4, KC=4)
    gemm_r<0, 4, 4><<<256, 256, 0, stream>>>(P0t, Wet, (void*)h0, nullptr, nullptr, 0);

    // recurrent steps (K=4096: NW=4, KC=32)
    for (int t = 0; t < 100; ++t) {
        const __hip_bfloat16* hprev = (t == 0) ? h0 : (G + (size_t)(t - 1) * 1048576);
        gemm_r<1, 4, 32><<<256, 256, 0, stream>>>(hprev, Wrt,
                                                  (void*)(G + (size_t)t * 1048576), v, W_in, t);
    }

    // decoder: 256x256 tiles, 200 blocks, 8 waves, B via LDS
    gemm_dec<<<200, 512, 0, stream>>>(G, Wdt, out);
}